// Round 2
// baseline (3204.753 us; speedup 1.0000x reference)
//
#include <hip/hip_runtime.h>
#include <math.h>

#define NN 50000
#define NE 800000
#define INF 512
#define HID 64
#define OUTF 40
#define NL 16

// ---------------- setup kernels ----------------

__global__ __launch_bounds__(256) void k_deg(const int* __restrict__ src, const int* __restrict__ dst,
                                             int* __restrict__ dout, int* __restrict__ din) {
    int e = blockIdx.x * 256 + threadIdx.x;
    if (e < NE) {
        atomicAdd(&dout[src[e]], 1);
        atomicAdd(&din[dst[e]], 1);
    }
}

__global__ __launch_bounds__(256) void k_norm(const int* __restrict__ dout, const int* __restrict__ din,
                                              float* __restrict__ ns, float* __restrict__ nd) {
    int i = blockIdx.x * 256 + threadIdx.x;
    if (i < NN) {
        ns[i] = 1.0f / sqrtf((float)max(dout[i], 1));
        nd[i] = 1.0f / sqrtf((float)max(din[i], 1));
    }
}

__global__ __launch_bounds__(256) void k_scanA(const int* __restrict__ din, int* __restrict__ incl,
                                               int* __restrict__ bsum) {
    __shared__ int lds[256];
    int i = blockIdx.x * 256 + threadIdx.x;
    int v = (i < NN) ? din[i] : 0;
    lds[threadIdx.x] = v;
    __syncthreads();
    for (int off = 1; off < 256; off <<= 1) {
        int t = (threadIdx.x >= off) ? lds[threadIdx.x - off] : 0;
        __syncthreads();
        lds[threadIdx.x] += t;
        __syncthreads();
    }
    if (i < NN) incl[i] = lds[threadIdx.x];
    if (threadIdx.x == 255) bsum[blockIdx.x] = lds[255];
}

__global__ __launch_bounds__(256) void k_scanB(int* __restrict__ bsum, int nb) {
    __shared__ int lds[256];
    int v = (threadIdx.x < nb) ? bsum[threadIdx.x] : 0;
    lds[threadIdx.x] = v;
    __syncthreads();
    for (int off = 1; off < 256; off <<= 1) {
        int t = (threadIdx.x >= off) ? lds[threadIdx.x - off] : 0;
        __syncthreads();
        lds[threadIdx.x] += t;
        __syncthreads();
    }
    if (threadIdx.x < nb) bsum[threadIdx.x] = lds[threadIdx.x] - v;  // exclusive
}

__global__ __launch_bounds__(256) void k_scanC(const int* __restrict__ incl, const int* __restrict__ din,
                                               const int* __restrict__ bsum, int* __restrict__ row_start,
                                               int* __restrict__ cursor) {
    int i = blockIdx.x * 256 + threadIdx.x;
    if (i < NN) {
        int rs = incl[i] - din[i] + bsum[i >> 8];
        row_start[i] = rs;
        cursor[i] = rs;
    }
}

__global__ __launch_bounds__(256) void k_fill(const int* __restrict__ src, const int* __restrict__ dst,
                                              int* __restrict__ cursor, int* __restrict__ col) {
    int e = blockIdx.x * 256 + threadIdx.x;
    if (e < NE) {
        int d = dst[e];
        int p = atomicAdd(&cursor[d], 1);
        col[p] = src[e];
    }
}

// premix weights: w1p = beta*W1 + (1-beta)*I, w2p likewise
__global__ __launch_bounds__(256) void k_wprep(const float* __restrict__ W1, const float* __restrict__ W2,
                                               float* __restrict__ w1p, float* __restrict__ w2p) {
    int i = blockIdx.x * 256 + threadIdx.x;
    if (i < NL * HID * HID) {
        int l = i >> 12;
        int rc = i & 4095;
        int r = rc >> 6;
        int c = rc & 63;
        float beta = logf(0.5f / (float)(l + 1) + 1.0f);
        float d = (r == c) ? (1.0f - beta) : 0.0f;
        w1p[i] = beta * W1[i] + d;
        w2p[i] = beta * W2[i] + d;
    }
}

// ---------------- h0 GEMM: thread = (node, 16-col group). Writes hs = relu(.)*ns, f0 = 0.1*relu(.) ----------------
__global__ __launch_bounds__(256) void k_gemm0(const float* __restrict__ feat, const float* __restrict__ Win,
                                               const float* __restrict__ bin, const float* __restrict__ ns,
                                               float* __restrict__ hs, float* __restrict__ f0) {
    int gid = blockIdx.x * 256 + threadIdx.x;
    int node = gid >> 2;
    int cg = (gid & 3) << 4;  // 0,16,32,48
    if (node >= NN) return;
    float acc[16];
#pragma unroll
    for (int c = 0; c < 16; c++) acc[c] = 0.0f;
    const float4* frow = (const float4*)(feat + (size_t)node * INF);
    for (int kk = 0; kk < INF; kk += 4) {
        float4 a = frow[kk >> 2];
        float av[4] = {a.x, a.y, a.z, a.w};
#pragma unroll
        for (int j = 0; j < 4; j++) {
            const float4* wr = (const float4*)(Win + (size_t)(kk + j) * HID + cg);
            float4 w0 = wr[0], w1 = wr[1], w2 = wr[2], w3 = wr[3];
            acc[0] += av[j] * w0.x;  acc[1] += av[j] * w0.y;
            acc[2] += av[j] * w0.z;  acc[3] += av[j] * w0.w;
            acc[4] += av[j] * w1.x;  acc[5] += av[j] * w1.y;
            acc[6] += av[j] * w1.z;  acc[7] += av[j] * w1.w;
            acc[8] += av[j] * w2.x;  acc[9] += av[j] * w2.y;
            acc[10] += av[j] * w2.z; acc[11] += av[j] * w2.w;
            acc[12] += av[j] * w3.x; acc[13] += av[j] * w3.y;
            acc[14] += av[j] * w3.z; acc[15] += av[j] * w3.w;
        }
    }
    float nsv = ns[node];
    const float* bp = bin + cg;
    float4* hsp = (float4*)(hs + (size_t)node * HID + cg);
    float4* f0p = (float4*)(f0 + (size_t)node * HID + cg);
#pragma unroll
    for (int c4 = 0; c4 < 4; c4++) {
        float r0 = fmaxf(acc[c4 * 4 + 0] + bp[c4 * 4 + 0], 0.0f);
        float r1 = fmaxf(acc[c4 * 4 + 1] + bp[c4 * 4 + 1], 0.0f);
        float r2 = fmaxf(acc[c4 * 4 + 2] + bp[c4 * 4 + 2], 0.0f);
        float r3 = fmaxf(acc[c4 * 4 + 3] + bp[c4 * 4 + 3], 0.0f);
        float4 vs = {r0 * nsv, r1 * nsv, r2 * nsv, r3 * nsv};
        hsp[c4] = vs;
        float4 vf = {r0 * 0.1f, r1 * 0.1f, r2 * 0.1f, r3 * 0.1f};
        f0p[c4] = vf;
    }
}

// ---------------- aggregation: f[n] = 0.9 * nd[n] * sum_{row n} hs[col[e]]; wave/node, lane=dim ----------------
__global__ __launch_bounds__(256) void k_agg(const float* __restrict__ hs, const int* __restrict__ col,
                                             const int* __restrict__ row_start, const int* __restrict__ din,
                                             const float* __restrict__ nd, float* __restrict__ f) {
    int n = (blockIdx.x * 256 + threadIdx.x) >> 6;
    int lane = threadIdx.x & 63;
    int base = row_start[n];
    int deg = din[n];
    float acc = 0.0f;
    for (int done = 0; done < deg;) {
        int cnt = min(64, deg - done);
        int idxv = (lane < cnt) ? col[base + done + lane] : 0;
        int i = 0;
        for (; i + 8 <= cnt; i += 8) {
            int s0 = __shfl(idxv, i, 64);
            int s1 = __shfl(idxv, i + 1, 64);
            int s2 = __shfl(idxv, i + 2, 64);
            int s3 = __shfl(idxv, i + 3, 64);
            int s4 = __shfl(idxv, i + 4, 64);
            int s5 = __shfl(idxv, i + 5, 64);
            int s6 = __shfl(idxv, i + 6, 64);
            int s7 = __shfl(idxv, i + 7, 64);
            float v0 = hs[s0 * HID + lane];
            float v1 = hs[s1 * HID + lane];
            float v2 = hs[s2 * HID + lane];
            float v3 = hs[s3 * HID + lane];
            float v4 = hs[s4 * HID + lane];
            float v5 = hs[s5 * HID + lane];
            float v6 = hs[s6 * HID + lane];
            float v7 = hs[s7 * HID + lane];
            acc += ((v0 + v1) + (v2 + v3)) + ((v4 + v5) + (v6 + v7));
        }
        for (; i < cnt; ++i) {
            int s = __shfl(idxv, i, 64);
            acc += hs[s * HID + lane];
        }
        done += cnt;
    }
    f[n * HID + lane] = 0.9f * nd[n] * acc;
}

// ---------------- layer matmul: thread = (node, 16-col group); h write only on last layer ----------------
__global__ __launch_bounds__(256) void k_mm(const float* __restrict__ f, const float* __restrict__ f0,
                                            const float* __restrict__ w1p, const float* __restrict__ w2p,
                                            const float* __restrict__ bias, const float* __restrict__ ns,
                                            float* __restrict__ h, float* __restrict__ hs, int write_h) {
    int gid = blockIdx.x * 256 + threadIdx.x;
    int node = gid >> 2;
    int cg = (gid & 3) << 4;
    if (node >= NN) return;
    float acc[16];
#pragma unroll
    for (int c = 0; c < 16; c++) acc[c] = 0.0f;
    const float4* fr = (const float4*)(f + (size_t)node * HID);
    const float4* f0r = (const float4*)(f0 + (size_t)node * HID);
    for (int kk = 0; kk < HID; kk += 4) {
        float4 a = fr[kk >> 2];
        float4 a0 = f0r[kk >> 2];
        float av[4] = {a.x, a.y, a.z, a.w};
        float a0v[4] = {a0.x, a0.y, a0.z, a0.w};
#pragma unroll
        for (int j = 0; j < 4; j++) {
            const float4* w1r = (const float4*)(w1p + (size_t)(kk + j) * HID + cg);
            const float4* w2r = (const float4*)(w2p + (size_t)(kk + j) * HID + cg);
#pragma unroll
            for (int q = 0; q < 4; q++) {
                float4 w1v = w1r[q];
                float4 w2v = w2r[q];
                acc[q * 4 + 0] += av[j] * w1v.x + a0v[j] * w2v.x;
                acc[q * 4 + 1] += av[j] * w1v.y + a0v[j] * w2v.y;
                acc[q * 4 + 2] += av[j] * w1v.z + a0v[j] * w2v.z;
                acc[q * 4 + 3] += av[j] * w1v.w + a0v[j] * w2v.w;
            }
        }
    }
    float nsv = ns[node];
    const float* bp = bias + cg;
    float4* hsp = (float4*)(hs + (size_t)node * HID + cg);
#pragma unroll
    for (int c4 = 0; c4 < 4; c4++) {
        float r0 = fmaxf(acc[c4 * 4 + 0] + bp[c4 * 4 + 0], 0.0f);
        float r1 = fmaxf(acc[c4 * 4 + 1] + bp[c4 * 4 + 1], 0.0f);
        float r2 = fmaxf(acc[c4 * 4 + 2] + bp[c4 * 4 + 2], 0.0f);
        float r3 = fmaxf(acc[c4 * 4 + 3] + bp[c4 * 4 + 3], 0.0f);
        float4 vs = {r0 * nsv, r1 * nsv, r2 * nsv, r3 * nsv};
        hsp[c4] = vs;
        if (write_h) {
            float4 v = {r0, r1, r2, r3};
            ((float4*)(h + (size_t)node * HID + cg))[c4] = v;
        }
    }
}

// ---------------- output: thread = (node, 20-col half); pair lse reduce via shfl_xor ----------------
__global__ __launch_bounds__(256) void k_out(const float* __restrict__ h, const float* __restrict__ Wout,
                                             const float* __restrict__ bout, float* __restrict__ out) {
    int gid = blockIdx.x * 256 + threadIdx.x;
    int node = gid >> 1;
    int half = (gid & 1) * 20;
    if (node >= NN) return;
    float acc[20];
#pragma unroll
    for (int c = 0; c < 20; c++) acc[c] = 0.0f;
    const float4* hr = (const float4*)(h + (size_t)node * HID);
    for (int kk = 0; kk < HID; kk += 4) {
        float4 a = hr[kk >> 2];
        float av[4] = {a.x, a.y, a.z, a.w};
#pragma unroll
        for (int j = 0; j < 4; j++) {
            const float4* wr = (const float4*)(Wout + (size_t)(kk + j) * OUTF + half);
#pragma unroll
            for (int q = 0; q < 5; q++) {
                float4 w = wr[q];
                acc[q * 4 + 0] += av[j] * w.x;
                acc[q * 4 + 1] += av[j] * w.y;
                acc[q * 4 + 2] += av[j] * w.z;
                acc[q * 4 + 3] += av[j] * w.w;
            }
        }
    }
#pragma unroll
    for (int c = 0; c < 20; c++) acc[c] += bout[half + c];
    float mx = acc[0];
#pragma unroll
    for (int c = 1; c < 20; c++) mx = fmaxf(mx, acc[c]);
    mx = fmaxf(mx, __shfl_xor(mx, 1, 64));
    float s = 0.0f;
#pragma unroll
    for (int c = 0; c < 20; c++) s += expf(acc[c] - mx);
    s += __shfl_xor(s, 1, 64);
    float lse = logf(s) + mx;
    float4* op = (float4*)(out + (size_t)node * OUTF + half);
#pragma unroll
    for (int q = 0; q < 5; q++) {
        float4 v;
        v.x = acc[q * 4 + 0] - lse;
        v.y = acc[q * 4 + 1] - lse;
        v.z = acc[q * 4 + 2] - lse;
        v.w = acc[q * 4 + 3] - lse;
        op[q] = v;
    }
}

extern "C" void kernel_launch(void* const* d_in, const int* in_sizes, int n_in,
                              void* d_out, int out_size, void* d_ws, size_t ws_size,
                              hipStream_t stream) {
    const float* feat = (const float*)d_in[0];
    const float* Win  = (const float*)d_in[1];
    const float* bin  = (const float*)d_in[2];
    const float* W1   = (const float*)d_in[3];
    const float* W2   = (const float*)d_in[4];
    const float* bvec = (const float*)d_in[5];
    const float* Wout = (const float*)d_in[6];
    const float* bout = (const float*)d_in[7];
    const int*   src  = (const int*)d_in[8];
    const int*   dst  = (const int*)d_in[9];
    float* out = (float*)d_out;

    char* ws = (char*)d_ws;
    size_t off = 0;
    auto take = [&](size_t bytes) {
        void* p = ws + off;
        off += (bytes + 255) & ~(size_t)255;
        return p;
    };
    int* deg_out   = (int*)take(NN * 4);
    int* deg_in    = (int*)take(NN * 4);
    int* incl      = (int*)take(NN * 4);
    int* bsum      = (int*)take(256 * 4);
    int* row_start = (int*)take(NN * 4);
    int* cursor    = (int*)take(NN * 4);
    int* col       = (int*)take(NE * 4);
    float* nsrc    = (float*)take(NN * 4);
    float* ndst    = (float*)take(NN * 4);
    float* w1p     = (float*)take((size_t)NL * HID * HID * 4);
    float* w2p     = (float*)take((size_t)NL * HID * HID * 4);
    float* f0      = (float*)take((size_t)NN * HID * 4);
    float* hbuf    = (float*)take((size_t)NN * HID * 4);
    float* hsbuf   = (float*)take((size_t)NN * HID * 4);
    float* fbuf    = (float*)take((size_t)NN * HID * 4);

    const int NB_N = (NN + 255) / 256;   // 196
    const int NB_E = (NE + 255) / 256;   // 3125
    const int NB_G = (NN * 4 + 255) / 256;  // 782
    const int NB_O = (NN * 2 + 255) / 256;  // 391

    hipMemsetAsync(deg_out, 0, NN * 4, stream);
    hipMemsetAsync(deg_in, 0, NN * 4, stream);

    k_deg<<<NB_E, 256, 0, stream>>>(src, dst, deg_out, deg_in);
    k_norm<<<NB_N, 256, 0, stream>>>(deg_out, deg_in, nsrc, ndst);
    k_scanA<<<NB_N, 256, 0, stream>>>(deg_in, incl, bsum);
    k_scanB<<<1, 256, 0, stream>>>(bsum, NB_N);
    k_scanC<<<NB_N, 256, 0, stream>>>(incl, deg_in, bsum, row_start, cursor);
    k_fill<<<NB_E, 256, 0, stream>>>(src, dst, cursor, col);
    k_wprep<<<(NL * HID * HID + 255) / 256, 256, 0, stream>>>(W1, W2, w1p, w2p);
    k_gemm0<<<NB_G, 256, 0, stream>>>(feat, Win, bin, nsrc, hsbuf, f0);

    for (int l = 0; l < NL; ++l) {
        k_agg<<<NN / 4, 256, 0, stream>>>(hsbuf, col, row_start, deg_in, ndst, fbuf);
        k_mm<<<NB_G, 256, 0, stream>>>(fbuf, f0, w1p + l * HID * HID, w2p + l * HID * HID,
                                       bvec + l * HID, nsrc, hbuf, hsbuf, (l == NL - 1) ? 1 : 0);
    }
    k_out<<<NB_O, 256, 0, stream>>>(hbuf, Wout, bout, out);
}

// Round 3
// 1904.085 us; speedup vs baseline: 1.6831x; 1.6831x over previous
//
#include <hip/hip_runtime.h>
#include <math.h>

#define NN 50000
#define NE 800000
#define INF 512
#define HID 64
#define OUTF 40
#define NL 16

// ---------------- setup kernels ----------------

__global__ __launch_bounds__(256) void k_deg(const int* __restrict__ src, const int* __restrict__ dst,
                                             int* __restrict__ dout, int* __restrict__ din) {
    int e = blockIdx.x * 256 + threadIdx.x;
    if (e < NE) {
        atomicAdd(&dout[src[e]], 1);
        atomicAdd(&din[dst[e]], 1);
    }
}

__global__ __launch_bounds__(256) void k_norm(const int* __restrict__ dout, const int* __restrict__ din,
                                              float* __restrict__ ns, float* __restrict__ nd) {
    int i = blockIdx.x * 256 + threadIdx.x;
    if (i < NN) {
        ns[i] = 1.0f / sqrtf((float)max(dout[i], 1));
        nd[i] = 1.0f / sqrtf((float)max(din[i], 1));
    }
}

__global__ __launch_bounds__(256) void k_scanA(const int* __restrict__ din, int* __restrict__ incl,
                                               int* __restrict__ bsum) {
    __shared__ int lds[256];
    int i = blockIdx.x * 256 + threadIdx.x;
    int v = (i < NN) ? din[i] : 0;
    lds[threadIdx.x] = v;
    __syncthreads();
    for (int off = 1; off < 256; off <<= 1) {
        int t = (threadIdx.x >= off) ? lds[threadIdx.x - off] : 0;
        __syncthreads();
        lds[threadIdx.x] += t;
        __syncthreads();
    }
    if (i < NN) incl[i] = lds[threadIdx.x];
    if (threadIdx.x == 255) bsum[blockIdx.x] = lds[255];
}

__global__ __launch_bounds__(256) void k_scanB(int* __restrict__ bsum, int nb) {
    __shared__ int lds[256];
    int v = (threadIdx.x < nb) ? bsum[threadIdx.x] : 0;
    lds[threadIdx.x] = v;
    __syncthreads();
    for (int off = 1; off < 256; off <<= 1) {
        int t = (threadIdx.x >= off) ? lds[threadIdx.x - off] : 0;
        __syncthreads();
        lds[threadIdx.x] += t;
        __syncthreads();
    }
    if (threadIdx.x < nb) bsum[threadIdx.x] = lds[threadIdx.x] - v;  // exclusive
}

__global__ __launch_bounds__(256) void k_scanC(const int* __restrict__ incl, const int* __restrict__ din,
                                               const int* __restrict__ bsum, int* __restrict__ row_start,
                                               int* __restrict__ cursor) {
    int i = blockIdx.x * 256 + threadIdx.x;
    if (i < NN) {
        int rs = incl[i] - din[i] + bsum[i >> 8];
        row_start[i] = rs;
        cursor[i] = rs;
    }
}

__global__ __launch_bounds__(256) void k_fill(const int* __restrict__ src, const int* __restrict__ dst,
                                              int* __restrict__ cursor, int* __restrict__ col) {
    int e = blockIdx.x * 256 + threadIdx.x;
    if (e < NE) {
        int d = dst[e];
        int p = atomicAdd(&cursor[d], 1);
        col[p] = src[e];
    }
}

// premix weights: w1p = beta*W1 + (1-beta)*I, w2p likewise
__global__ __launch_bounds__(256) void k_wprep(const float* __restrict__ W1, const float* __restrict__ W2,
                                               float* __restrict__ w1p, float* __restrict__ w2p) {
    int i = blockIdx.x * 256 + threadIdx.x;
    if (i < NL * HID * HID) {
        int l = i >> 12;
        int rc = i & 4095;
        int r = rc >> 6;
        int c = rc & 63;
        float beta = logf(0.5f / (float)(l + 1) + 1.0f);
        float d = (r == c) ? (1.0f - beta) : 0.0f;
        w1p[i] = beta * W1[i] + d;
        w2p[i] = beta * W2[i] + d;
    }
}

// ---------------- h0 GEMM: lane = node, wave = 16-col group (wave-uniform weights -> scalar loads) ----------------
__global__ __launch_bounds__(256) void k_gemm0(const float* __restrict__ feat, const float* __restrict__ Win,
                                               const float* __restrict__ bin, const float* __restrict__ ns,
                                               float* __restrict__ hs, float* __restrict__ f0) {
    int lane = threadIdx.x & 63;
    int cg = __builtin_amdgcn_readfirstlane((threadIdx.x >> 6) & 3) * 16;  // SGPR -> scalar weight loads
    int node = blockIdx.x * 64 + lane;
    int nodec = min(node, NN - 1);
    const float4* frow = (const float4*)(feat + (size_t)nodec * INF);
    const float* wbase = Win + cg;  // row k at wbase + k*HID, wave-uniform
    float acc[16];
#pragma unroll
    for (int c = 0; c < 16; c++) acc[c] = 0.0f;
    for (int kk = 0; kk < INF / 4; ++kk) {
        float4 a = frow[kk];
        float av[4] = {a.x, a.y, a.z, a.w};
#pragma unroll
        for (int j = 0; j < 4; j++) {
            const float* wr = wbase + (size_t)(kk * 4 + j) * HID;
#pragma unroll
            for (int c = 0; c < 16; c++) acc[c] += av[j] * wr[c];
        }
    }
    if (node < NN) {
        float nsv = ns[node];
        const float* bp = bin + cg;
        float4* hsp = (float4*)(hs + (size_t)node * HID + cg);
        float4* f0p = (float4*)(f0 + (size_t)node * HID + cg);
#pragma unroll
        for (int c4 = 0; c4 < 4; c4++) {
            float r0 = fmaxf(acc[c4 * 4 + 0] + bp[c4 * 4 + 0], 0.0f);
            float r1 = fmaxf(acc[c4 * 4 + 1] + bp[c4 * 4 + 1], 0.0f);
            float r2 = fmaxf(acc[c4 * 4 + 2] + bp[c4 * 4 + 2], 0.0f);
            float r3 = fmaxf(acc[c4 * 4 + 3] + bp[c4 * 4 + 3], 0.0f);
            float4 vs = {r0 * nsv, r1 * nsv, r2 * nsv, r3 * nsv};
            hsp[c4] = vs;
            float4 vf = {r0 * 0.1f, r1 * 0.1f, r2 * 0.1f, r3 * 0.1f};
            f0p[c4] = vf;
        }
    }
}

// ---------------- aggregation: f[n] = 0.9 * nd[n] * sum_{row n} hs[col[e]]; wave/node, lane=dim ----------------
__global__ __launch_bounds__(256) void k_agg(const float* __restrict__ hs, const int* __restrict__ col,
                                             const int* __restrict__ row_start, const int* __restrict__ din,
                                             const float* __restrict__ nd, float* __restrict__ f) {
    int n = (blockIdx.x * 256 + threadIdx.x) >> 6;
    int lane = threadIdx.x & 63;
    int base = row_start[n];
    int deg = din[n];
    float acc = 0.0f;
    for (int done = 0; done < deg;) {
        int cnt = min(64, deg - done);
        int idxv = (lane < cnt) ? col[base + done + lane] : 0;
        int i = 0;
        for (; i + 8 <= cnt; i += 8) {
            int s0 = __shfl(idxv, i, 64);
            int s1 = __shfl(idxv, i + 1, 64);
            int s2 = __shfl(idxv, i + 2, 64);
            int s3 = __shfl(idxv, i + 3, 64);
            int s4 = __shfl(idxv, i + 4, 64);
            int s5 = __shfl(idxv, i + 5, 64);
            int s6 = __shfl(idxv, i + 6, 64);
            int s7 = __shfl(idxv, i + 7, 64);
            float v0 = hs[s0 * HID + lane];
            float v1 = hs[s1 * HID + lane];
            float v2 = hs[s2 * HID + lane];
            float v3 = hs[s3 * HID + lane];
            float v4 = hs[s4 * HID + lane];
            float v5 = hs[s5 * HID + lane];
            float v6 = hs[s6 * HID + lane];
            float v7 = hs[s7 * HID + lane];
            acc += ((v0 + v1) + (v2 + v3)) + ((v4 + v5) + (v6 + v7));
        }
        for (; i < cnt; ++i) {
            int s = __shfl(idxv, i, 64);
            acc += hs[s * HID + lane];
        }
        done += cnt;
    }
    f[n * HID + lane] = 0.9f * nd[n] * acc;
}

// ---------------- layer matmul: lane = node, wave = 16-col group; weights scalar ----------------
__global__ __launch_bounds__(256) void k_mm(const float* __restrict__ f, const float* __restrict__ f0,
                                            const float* __restrict__ w1p, const float* __restrict__ w2p,
                                            const float* __restrict__ bias, const float* __restrict__ ns,
                                            float* __restrict__ h, float* __restrict__ hs, int write_h) {
    int lane = threadIdx.x & 63;
    int cg = __builtin_amdgcn_readfirstlane((threadIdx.x >> 6) & 3) * 16;
    int node = blockIdx.x * 64 + lane;
    int nodec = min(node, NN - 1);
    const float4* fr = (const float4*)(f + (size_t)nodec * HID);
    const float4* f0r = (const float4*)(f0 + (size_t)nodec * HID);
    const float* w1b = w1p + cg;
    const float* w2b = w2p + cg;
    float acc[16];
#pragma unroll
    for (int c = 0; c < 16; c++) acc[c] = 0.0f;
    for (int kk = 0; kk < HID / 4; ++kk) {
        float4 a = fr[kk];
        float4 a0 = f0r[kk];
        float av[4] = {a.x, a.y, a.z, a.w};
        float a0v[4] = {a0.x, a0.y, a0.z, a0.w};
#pragma unroll
        for (int j = 0; j < 4; j++) {
            const float* w1r = w1b + (size_t)(kk * 4 + j) * HID;
            const float* w2r = w2b + (size_t)(kk * 4 + j) * HID;
#pragma unroll
            for (int c = 0; c < 16; c++) acc[c] += av[j] * w1r[c] + a0v[j] * w2r[c];
        }
    }
    if (node < NN) {
        float nsv = ns[node];
        const float* bp = bias + cg;
        float4* hsp = (float4*)(hs + (size_t)node * HID + cg);
#pragma unroll
        for (int c4 = 0; c4 < 4; c4++) {
            float r0 = fmaxf(acc[c4 * 4 + 0] + bp[c4 * 4 + 0], 0.0f);
            float r1 = fmaxf(acc[c4 * 4 + 1] + bp[c4 * 4 + 1], 0.0f);
            float r2 = fmaxf(acc[c4 * 4 + 2] + bp[c4 * 4 + 2], 0.0f);
            float r3 = fmaxf(acc[c4 * 4 + 3] + bp[c4 * 4 + 3], 0.0f);
            float4 vs = {r0 * nsv, r1 * nsv, r2 * nsv, r3 * nsv};
            hsp[c4] = vs;
            if (write_h) {
                float4 v = {r0, r1, r2, r3};
                ((float4*)(h + (size_t)node * HID + cg))[c4] = v;
            }
        }
    }
}

// ---------------- output: lane = node, full 40 cols; weights scalar ----------------
__global__ __launch_bounds__(256) void k_out(const float* __restrict__ h, const float* __restrict__ Wout,
                                             const float* __restrict__ bout, float* __restrict__ out) {
    int node = blockIdx.x * 256 + threadIdx.x;
    int nodec = min(node, NN - 1);
    float acc[OUTF];
#pragma unroll
    for (int c = 0; c < OUTF; c++) acc[c] = 0.0f;
    const float4* hr = (const float4*)(h + (size_t)nodec * HID);
    for (int kk = 0; kk < HID / 4; ++kk) {
        float4 a = hr[kk];
        float av[4] = {a.x, a.y, a.z, a.w};
#pragma unroll
        for (int j = 0; j < 4; j++) {
            const float* wr = Wout + (size_t)(kk * 4 + j) * OUTF;
#pragma unroll
            for (int c = 0; c < OUTF; c++) acc[c] += av[j] * wr[c];
        }
    }
#pragma unroll
    for (int c = 0; c < OUTF; c++) acc[c] += bout[c];
    float mx = acc[0];
#pragma unroll
    for (int c = 1; c < OUTF; c++) mx = fmaxf(mx, acc[c]);
    float s = 0.0f;
#pragma unroll
    for (int c = 0; c < OUTF; c++) s += expf(acc[c] - mx);
    float lse = logf(s) + mx;
    if (node < NN) {
        float4* op = (float4*)(out + (size_t)node * OUTF);
#pragma unroll
        for (int q = 0; q < OUTF / 4; q++) {
            float4 v;
            v.x = acc[q * 4 + 0] - lse;
            v.y = acc[q * 4 + 1] - lse;
            v.z = acc[q * 4 + 2] - lse;
            v.w = acc[q * 4 + 3] - lse;
            op[q] = v;
        }
    }
}

extern "C" void kernel_launch(void* const* d_in, const int* in_sizes, int n_in,
                              void* d_out, int out_size, void* d_ws, size_t ws_size,
                              hipStream_t stream) {
    const float* feat = (const float*)d_in[0];
    const float* Win  = (const float*)d_in[1];
    const float* bin  = (const float*)d_in[2];
    const float* W1   = (const float*)d_in[3];
    const float* W2   = (const float*)d_in[4];
    const float* bvec = (const float*)d_in[5];
    const float* Wout = (const float*)d_in[6];
    const float* bout = (const float*)d_in[7];
    const int*   src  = (const int*)d_in[8];
    const int*   dst  = (const int*)d_in[9];
    float* out = (float*)d_out;

    char* ws = (char*)d_ws;
    size_t off = 0;
    auto take = [&](size_t bytes) {
        void* p = ws + off;
        off += (bytes + 255) & ~(size_t)255;
        return p;
    };
    int* deg_out   = (int*)take(NN * 4);
    int* deg_in    = (int*)take(NN * 4);
    int* incl      = (int*)take(NN * 4);
    int* bsum      = (int*)take(256 * 4);
    int* row_start = (int*)take(NN * 4);
    int* cursor    = (int*)take(NN * 4);
    int* col       = (int*)take(NE * 4);
    float* nsrc    = (float*)take(NN * 4);
    float* ndst    = (float*)take(NN * 4);
    float* w1p     = (float*)take((size_t)NL * HID * HID * 4);
    float* w2p     = (float*)take((size_t)NL * HID * HID * 4);
    float* f0      = (float*)take((size_t)NN * HID * 4);
    float* hbuf    = (float*)take((size_t)NN * HID * 4);
    float* hsbuf   = (float*)take((size_t)NN * HID * 4);
    float* fbuf    = (float*)take((size_t)NN * HID * 4);

    const int NB_N = (NN + 255) / 256;      // 196
    const int NB_E = (NE + 255) / 256;      // 3125
    const int NB_W = (NN + 63) / 64;        // 782: 64 nodes/block, 4 waves = 4 col groups

    hipMemsetAsync(deg_out, 0, NN * 4, stream);
    hipMemsetAsync(deg_in, 0, NN * 4, stream);

    k_deg<<<NB_E, 256, 0, stream>>>(src, dst, deg_out, deg_in);
    k_norm<<<NB_N, 256, 0, stream>>>(deg_out, deg_in, nsrc, ndst);
    k_scanA<<<NB_N, 256, 0, stream>>>(deg_in, incl, bsum);
    k_scanB<<<1, 256, 0, stream>>>(bsum, NB_N);
    k_scanC<<<NB_N, 256, 0, stream>>>(incl, deg_in, bsum, row_start, cursor);
    k_fill<<<NB_E, 256, 0, stream>>>(src, dst, cursor, col);
    k_wprep<<<(NL * HID * HID + 255) / 256, 256, 0, stream>>>(W1, W2, w1p, w2p);
    k_gemm0<<<NB_W, 256, 0, stream>>>(feat, Win, bin, nsrc, hsbuf, f0);

    for (int l = 0; l < NL; ++l) {
        k_agg<<<NN / 4, 256, 0, stream>>>(hsbuf, col, row_start, deg_in, ndst, fbuf);
        k_mm<<<NB_W, 256, 0, stream>>>(fbuf, f0, w1p + l * HID * HID, w2p + l * HID * HID,
                                       bvec + l * HID, nsrc, hbuf, hsbuf, (l == NL - 1) ? 1 : 0);
    }
    k_out<<<NB_N, 256, 0, stream>>>(hbuf, Wout, bout, out);
}

// Round 4
// 1531.736 us; speedup vs baseline: 2.0922x; 1.2431x over previous
//
#include <hip/hip_runtime.h>
#include <math.h>

#define NN 50000
#define NE 800000
#define INF 512
#define HID 64
#define OUTF 40
#define NL 16
#define PADN 65

// ---------------- setup kernels ----------------

__global__ __launch_bounds__(256) void k_deg(const int* __restrict__ src, const int* __restrict__ dst,
                                             int* __restrict__ dout, int* __restrict__ din) {
    int e = blockIdx.x * 256 + threadIdx.x;
    if (e < NE) {
        atomicAdd(&dout[src[e]], 1);
        atomicAdd(&din[dst[e]], 1);
    }
}

__global__ __launch_bounds__(256) void k_norm(const int* __restrict__ dout, const int* __restrict__ din,
                                              float* __restrict__ ns, float* __restrict__ nd) {
    int i = blockIdx.x * 256 + threadIdx.x;
    if (i < NN) {
        ns[i] = 1.0f / sqrtf((float)max(dout[i], 1));
        nd[i] = 1.0f / sqrtf((float)max(din[i], 1));
    }
}

__global__ __launch_bounds__(256) void k_scanA(const int* __restrict__ din, int* __restrict__ incl,
                                               int* __restrict__ bsum) {
    __shared__ int lds[256];
    int i = blockIdx.x * 256 + threadIdx.x;
    int v = (i < NN) ? din[i] : 0;
    lds[threadIdx.x] = v;
    __syncthreads();
    for (int off = 1; off < 256; off <<= 1) {
        int t = (threadIdx.x >= off) ? lds[threadIdx.x - off] : 0;
        __syncthreads();
        lds[threadIdx.x] += t;
        __syncthreads();
    }
    if (i < NN) incl[i] = lds[threadIdx.x];
    if (threadIdx.x == 255) bsum[blockIdx.x] = lds[255];
}

__global__ __launch_bounds__(256) void k_scanB(int* __restrict__ bsum, int nb) {
    __shared__ int lds[256];
    int v = (threadIdx.x < nb) ? bsum[threadIdx.x] : 0;
    lds[threadIdx.x] = v;
    __syncthreads();
    for (int off = 1; off < 256; off <<= 1) {
        int t = (threadIdx.x >= off) ? lds[threadIdx.x - off] : 0;
        __syncthreads();
        lds[threadIdx.x] += t;
        __syncthreads();
    }
    if (threadIdx.x < nb) bsum[threadIdx.x] = lds[threadIdx.x] - v;  // exclusive
}

__global__ __launch_bounds__(256) void k_scanC(const int* __restrict__ incl, const int* __restrict__ din,
                                               const int* __restrict__ bsum, int* __restrict__ row_start,
                                               int* __restrict__ cursor) {
    int i = blockIdx.x * 256 + threadIdx.x;
    if (i < NN) {
        int rs = incl[i] - din[i] + bsum[i >> 8];
        row_start[i] = rs;
        cursor[i] = rs;
    }
}

__global__ __launch_bounds__(256) void k_fill(const int* __restrict__ src, const int* __restrict__ dst,
                                              int* __restrict__ cursor, int* __restrict__ col) {
    int e = blockIdx.x * 256 + threadIdx.x;
    if (e < NE) {
        int d = dst[e];
        int p = atomicAdd(&cursor[d], 1);
        col[p] = src[e];
    }
}

__global__ __launch_bounds__(256) void k_wprep(const float* __restrict__ W1, const float* __restrict__ W2,
                                               float* __restrict__ w1p, float* __restrict__ w2p) {
    int i = blockIdx.x * 256 + threadIdx.x;
    if (i < NL * HID * HID) {
        int l = i >> 12;
        int rc = i & 4095;
        int r = rc >> 6;
        int c = rc & 63;
        float beta = logf(0.5f / (float)(l + 1) + 1.0f);
        float d = (r == c) ? (1.0f - beta) : 0.0f;
        w1p[i] = beta * W1[i] + d;
        w2p[i] = beta * W2[i] + d;
    }
}

// ---------------- h0 GEMM: lane = node, wave = 16-col group (scalar weight loads) ----------------
__global__ __launch_bounds__(256) void k_gemm0(const float* __restrict__ feat, const float* __restrict__ Win,
                                               const float* __restrict__ bin, const float* __restrict__ ns,
                                               float* __restrict__ hs, float* __restrict__ f0) {
    int lane = threadIdx.x & 63;
    int cg = __builtin_amdgcn_readfirstlane((threadIdx.x >> 6) & 3) * 16;
    int node = blockIdx.x * 64 + lane;
    int nodec = min(node, NN - 1);
    const float4* frow = (const float4*)(feat + (size_t)nodec * INF);
    const float* wbase = Win + cg;
    float acc[16];
#pragma unroll
    for (int c = 0; c < 16; c++) acc[c] = 0.0f;
    for (int kk = 0; kk < INF / 4; ++kk) {
        float4 a = frow[kk];
        float av[4] = {a.x, a.y, a.z, a.w};
#pragma unroll
        for (int j = 0; j < 4; j++) {
            const float* wr = wbase + (size_t)(kk * 4 + j) * HID;
#pragma unroll
            for (int c = 0; c < 16; c++) acc[c] += av[j] * wr[c];
        }
    }
    if (node < NN) {
        float nsv = ns[node];
        const float* bp = bin + cg;
        float4* hsp = (float4*)(hs + (size_t)node * HID + cg);
        float4* f0p = (float4*)(f0 + (size_t)node * HID + cg);
#pragma unroll
        for (int c4 = 0; c4 < 4; c4++) {
            float r0 = fmaxf(acc[c4 * 4 + 0] + bp[c4 * 4 + 0], 0.0f);
            float r1 = fmaxf(acc[c4 * 4 + 1] + bp[c4 * 4 + 1], 0.0f);
            float r2 = fmaxf(acc[c4 * 4 + 2] + bp[c4 * 4 + 2], 0.0f);
            float r3 = fmaxf(acc[c4 * 4 + 3] + bp[c4 * 4 + 3], 0.0f);
            float4 vs = {r0 * nsv, r1 * nsv, r2 * nsv, r3 * nsv};
            hsp[c4] = vs;
            float4 vf = {r0 * 0.1f, r1 * 0.1f, r2 * 0.1f, r3 * 0.1f};
            f0p[c4] = vf;
        }
    }
}

// ---------------- fused layer: agg (gather into LDS) + matmul (LDS activations, scalar weights) ----------------
// block = 64 nodes, 4 waves. fT/f0T stored TRANSPOSED [k][node] with pad 65.
__global__ __launch_bounds__(256) void k_layer(const float* __restrict__ hs_in, const int* __restrict__ col,
                                               const int* __restrict__ row_start, const int* __restrict__ din,
                                               const float* __restrict__ nd, const float* __restrict__ f0,
                                               const float* __restrict__ w1p, const float* __restrict__ w2p,
                                               const float* __restrict__ bias, const float* __restrict__ ns,
                                               float* __restrict__ h, float* __restrict__ hs_out, int write_h) {
    __shared__ float fT[HID * PADN];
    __shared__ float f0T[HID * PADN];
    int tid = threadIdx.x;
    int lane = tid & 63;
    int wv = tid >> 6;
    int nb = blockIdx.x * 64;

    // stage f0 rows -> LDS transposed (coalesced 16B global reads)
    for (int i = tid; i < 64 * 16; i += 256) {
        int nl = i >> 4;
        int c4 = i & 15;
        int n = min(nb + nl, NN - 1);
        float4 v = *(const float4*)(f0 + (size_t)n * HID + c4 * 4);
        f0T[(c4 * 4 + 0) * PADN + nl] = v.x;
        f0T[(c4 * 4 + 1) * PADN + nl] = v.y;
        f0T[(c4 * 4 + 2) * PADN + nl] = v.z;
        f0T[(c4 * 4 + 3) * PADN + nl] = v.w;
    }

    // aggregation: wave wv handles 16 nodes; lane = feature dim
    for (int i = 0; i < 16; ++i) {
        int nl = wv * 16 + i;
        int n = min(nb + nl, NN - 1);
        int base = row_start[n];
        int deg = din[n];
        float acc = 0.0f;
        for (int done = 0; done < deg;) {
            int cnt = min(64, deg - done);
            int idxv = (lane < cnt) ? col[base + done + lane] : 0;
            int e = 0;
            for (; e + 8 <= cnt; e += 8) {
                int s0 = __shfl(idxv, e, 64);
                int s1 = __shfl(idxv, e + 1, 64);
                int s2 = __shfl(idxv, e + 2, 64);
                int s3 = __shfl(idxv, e + 3, 64);
                int s4 = __shfl(idxv, e + 4, 64);
                int s5 = __shfl(idxv, e + 5, 64);
                int s6 = __shfl(idxv, e + 6, 64);
                int s7 = __shfl(idxv, e + 7, 64);
                float v0 = hs_in[s0 * HID + lane];
                float v1 = hs_in[s1 * HID + lane];
                float v2 = hs_in[s2 * HID + lane];
                float v3 = hs_in[s3 * HID + lane];
                float v4 = hs_in[s4 * HID + lane];
                float v5 = hs_in[s5 * HID + lane];
                float v6 = hs_in[s6 * HID + lane];
                float v7 = hs_in[s7 * HID + lane];
                acc += ((v0 + v1) + (v2 + v3)) + ((v4 + v5) + (v6 + v7));
            }
            for (; e < cnt; ++e) {
                int s = __shfl(idxv, e, 64);
                acc += hs_in[s * HID + lane];
            }
            done += cnt;
        }
        fT[lane * PADN + nl] = 0.9f * nd[n] * acc;  // bank-free (pad 65)
    }
    __syncthreads();

    // matmul: lane = node, wave = 16-col group; weights wave-uniform -> scalar loads
    int cg = __builtin_amdgcn_readfirstlane(wv) * 16;
    const float* w1b = w1p + cg;
    const float* w2b = w2p + cg;
    float acc[16];
#pragma unroll
    for (int c = 0; c < 16; c++) acc[c] = 0.0f;
    for (int kk = 0; kk < HID / 4; ++kk) {
#pragma unroll
        for (int j = 0; j < 4; j++) {
            int k = kk * 4 + j;
            float fk = fT[k * PADN + lane];
            float f0k = f0T[k * PADN + lane];
            const float* w1r = w1b + (size_t)k * HID;
            const float* w2r = w2b + (size_t)k * HID;
#pragma unroll
            for (int c = 0; c < 16; c++) acc[c] += fk * w1r[c] + f0k * w2r[c];
        }
    }
    int node = nb + lane;
    if (node < NN) {
        float nsv = ns[node];
        const float* bp = bias + cg;
        float4* hsp = (float4*)(hs_out + (size_t)node * HID + cg);
#pragma unroll
        for (int c4 = 0; c4 < 4; c4++) {
            float r0 = fmaxf(acc[c4 * 4 + 0] + bp[c4 * 4 + 0], 0.0f);
            float r1 = fmaxf(acc[c4 * 4 + 1] + bp[c4 * 4 + 1], 0.0f);
            float r2 = fmaxf(acc[c4 * 4 + 2] + bp[c4 * 4 + 2], 0.0f);
            float r3 = fmaxf(acc[c4 * 4 + 3] + bp[c4 * 4 + 3], 0.0f);
            float4 vs = {r0 * nsv, r1 * nsv, r2 * nsv, r3 * nsv};
            hsp[c4] = vs;
            if (write_h) {
                float4 v = {r0, r1, r2, r3};
                ((float4*)(h + (size_t)node * HID + cg))[c4] = v;
            }
        }
    }
}

// ---------------- output: block = 128 nodes; wave pair splits the 40 cols; LDS lse reduce ----------------
__global__ __launch_bounds__(256) void k_out(const float* __restrict__ h, const float* __restrict__ Wout,
                                             const float* __restrict__ bout, float* __restrict__ out) {
    __shared__ float red_mx[4][64];
    __shared__ float red_s[4][64];
    int tid = threadIdx.x;
    int lane = tid & 63;
    int wv = tid >> 6;
    int half = wv & 1;
    int grp = wv >> 1;
    int node = blockIdx.x * 128 + grp * 64 + lane;
    int nodec = min(node, NN - 1);
    float acc[20];
#pragma unroll
    for (int c = 0; c < 20; c++) acc[c] = 0.0f;
    const float4* hr = (const float4*)(h + (size_t)nodec * HID);
    const float* wb = Wout + half * 20;
    for (int kk = 0; kk < HID / 4; ++kk) {
        float4 a = hr[kk];
        float av[4] = {a.x, a.y, a.z, a.w};
#pragma unroll
        for (int j = 0; j < 4; j++) {
            const float* wr = wb + (size_t)(kk * 4 + j) * OUTF;
#pragma unroll
            for (int c = 0; c < 20; c++) acc[c] += av[j] * wr[c];
        }
    }
    const float* bp = bout + half * 20;
#pragma unroll
    for (int c = 0; c < 20; c++) acc[c] += bp[c];
    float mx = acc[0];
#pragma unroll
    for (int c = 1; c < 20; c++) mx = fmaxf(mx, acc[c]);
    red_mx[wv][lane] = mx;
    __syncthreads();
    float gmx = fmaxf(mx, red_mx[wv ^ 1][lane]);
    float s = 0.0f;
#pragma unroll
    for (int c = 0; c < 20; c++) s += expf(acc[c] - gmx);
    red_s[wv][lane] = s;
    __syncthreads();
    float lse = logf(s + red_s[wv ^ 1][lane]) + gmx;
    if (node < NN) {
        float4* op = (float4*)(out + (size_t)node * OUTF + half * 20);
#pragma unroll
        for (int q = 0; q < 5; q++) {
            float4 v;
            v.x = acc[q * 4 + 0] - lse;
            v.y = acc[q * 4 + 1] - lse;
            v.z = acc[q * 4 + 2] - lse;
            v.w = acc[q * 4 + 3] - lse;
            op[q] = v;
        }
    }
}

extern "C" void kernel_launch(void* const* d_in, const int* in_sizes, int n_in,
                              void* d_out, int out_size, void* d_ws, size_t ws_size,
                              hipStream_t stream) {
    const float* feat = (const float*)d_in[0];
    const float* Win  = (const float*)d_in[1];
    const float* bin  = (const float*)d_in[2];
    const float* W1   = (const float*)d_in[3];
    const float* W2   = (const float*)d_in[4];
    const float* bvec = (const float*)d_in[5];
    const float* Wout = (const float*)d_in[6];
    const float* bout = (const float*)d_in[7];
    const int*   src  = (const int*)d_in[8];
    const int*   dst  = (const int*)d_in[9];
    float* out = (float*)d_out;

    char* ws = (char*)d_ws;
    size_t off = 0;
    auto take = [&](size_t bytes) {
        void* p = ws + off;
        off += (bytes + 255) & ~(size_t)255;
        return p;
    };
    int* deg_out   = (int*)take(NN * 4);
    int* deg_in    = (int*)take(NN * 4);
    int* incl      = (int*)take(NN * 4);
    int* bsum      = (int*)take(256 * 4);
    int* row_start = (int*)take(NN * 4);
    int* cursor    = (int*)take(NN * 4);
    int* col       = (int*)take(NE * 4);
    float* nsrc    = (float*)take(NN * 4);
    float* ndst    = (float*)take(NN * 4);
    float* w1p     = (float*)take((size_t)NL * HID * HID * 4);
    float* w2p     = (float*)take((size_t)NL * HID * HID * 4);
    float* f0      = (float*)take((size_t)NN * HID * 4);
    float* hbuf    = (float*)take((size_t)NN * HID * 4);
    float* hsA     = (float*)take((size_t)NN * HID * 4);
    float* hsB     = (float*)take((size_t)NN * HID * 4);

    const int NB_N = (NN + 255) / 256;   // 196
    const int NB_E = (NE + 255) / 256;   // 3125
    const int NB_W = (NN + 63) / 64;     // 782
    const int NB_O = (NN + 127) / 128;   // 391

    hipMemsetAsync(deg_out, 0, NN * 4, stream);
    hipMemsetAsync(deg_in, 0, NN * 4, stream);

    k_deg<<<NB_E, 256, 0, stream>>>(src, dst, deg_out, deg_in);
    k_norm<<<NB_N, 256, 0, stream>>>(deg_out, deg_in, nsrc, ndst);
    k_scanA<<<NB_N, 256, 0, stream>>>(deg_in, incl, bsum);
    k_scanB<<<1, 256, 0, stream>>>(bsum, NB_N);
    k_scanC<<<NB_N, 256, 0, stream>>>(incl, deg_in, bsum, row_start, cursor);
    k_fill<<<NB_E, 256, 0, stream>>>(src, dst, cursor, col);
    k_wprep<<<(NL * HID * HID + 255) / 256, 256, 0, stream>>>(W1, W2, w1p, w2p);
    k_gemm0<<<NB_W, 256, 0, stream>>>(feat, Win, bin, nsrc, hsA, f0);

    // ping-pong hs buffers: k_layer gathers arbitrary rows of hs_in, so in-place update would race
    for (int l = 0; l < NL; ++l) {
        const float* hin = (l & 1) ? hsB : hsA;
        float* hout = (l & 1) ? hsA : hsB;
        k_layer<<<NB_W, 256, 0, stream>>>(hin, col, row_start, deg_in, ndst, f0,
                                          w1p + l * HID * HID, w2p + l * HID * HID,
                                          bvec + l * HID, nsrc, hbuf, hout, (l == NL - 1) ? 1 : 0);
    }
    k_out<<<NB_O, 256, 0, stream>>>(hbuf, Wout, bout, out);
}

// Round 5
// 1311.399 us; speedup vs baseline: 2.4438x; 1.1680x over previous
//
#include <hip/hip_runtime.h>
#include <math.h>

#define NN 50000
#define NE 800000
#define INF 512
#define HID 64
#define OUTF 40
#define NL 16
#define PADN 65

// ---------------- setup kernels ----------------

__global__ __launch_bounds__(256) void k_deg(const int* __restrict__ src, const int* __restrict__ dst,
                                             int* __restrict__ dout, int* __restrict__ din) {
    int e = blockIdx.x * 256 + threadIdx.x;
    if (e < NE) {
        atomicAdd(&dout[src[e]], 1);
        atomicAdd(&din[dst[e]], 1);
    }
}

__global__ __launch_bounds__(256) void k_norm(const int* __restrict__ dout, const int* __restrict__ din,
                                              float* __restrict__ ns, float* __restrict__ nd) {
    int i = blockIdx.x * 256 + threadIdx.x;
    if (i < NN) {
        ns[i] = 1.0f / sqrtf((float)max(dout[i], 1));
        nd[i] = 1.0f / sqrtf((float)max(din[i], 1));
    }
}

__global__ __launch_bounds__(256) void k_scanA(const int* __restrict__ din, int* __restrict__ incl,
                                               int* __restrict__ bsum) {
    __shared__ int lds[256];
    int i = blockIdx.x * 256 + threadIdx.x;
    int v = (i < NN) ? din[i] : 0;
    lds[threadIdx.x] = v;
    __syncthreads();
    for (int off = 1; off < 256; off <<= 1) {
        int t = (threadIdx.x >= off) ? lds[threadIdx.x - off] : 0;
        __syncthreads();
        lds[threadIdx.x] += t;
        __syncthreads();
    }
    if (i < NN) incl[i] = lds[threadIdx.x];
    if (threadIdx.x == 255) bsum[blockIdx.x] = lds[255];
}

__global__ __launch_bounds__(256) void k_scanB(int* __restrict__ bsum, int nb) {
    __shared__ int lds[256];
    int v = (threadIdx.x < nb) ? bsum[threadIdx.x] : 0;
    lds[threadIdx.x] = v;
    __syncthreads();
    for (int off = 1; off < 256; off <<= 1) {
        int t = (threadIdx.x >= off) ? lds[threadIdx.x - off] : 0;
        __syncthreads();
        lds[threadIdx.x] += t;
        __syncthreads();
    }
    if (threadIdx.x < nb) bsum[threadIdx.x] = lds[threadIdx.x] - v;  // exclusive
}

__global__ __launch_bounds__(256) void k_scanC(const int* __restrict__ incl, const int* __restrict__ din,
                                               const int* __restrict__ bsum, int* __restrict__ row_start,
                                               int* __restrict__ cursor) {
    int i = blockIdx.x * 256 + threadIdx.x;
    if (i < NN) {
        int rs = incl[i] - din[i] + bsum[i >> 8];
        row_start[i] = rs;
        cursor[i] = rs;
    }
}

__global__ __launch_bounds__(256) void k_fill(const int* __restrict__ src, const int* __restrict__ dst,
                                              int* __restrict__ cursor, int* __restrict__ col) {
    int e = blockIdx.x * 256 + threadIdx.x;
    if (e < NE) {
        int d = dst[e];
        int p = atomicAdd(&cursor[d], 1);
        col[p] = src[e];
    }
}

__global__ __launch_bounds__(256) void k_wprep(const float* __restrict__ W1, const float* __restrict__ W2,
                                               float* __restrict__ w1p, float* __restrict__ w2p) {
    int i = blockIdx.x * 256 + threadIdx.x;
    if (i < NL * HID * HID) {
        int l = i >> 12;
        int rc = i & 4095;
        int r = rc >> 6;
        int c = rc & 63;
        float beta = logf(0.5f / (float)(l + 1) + 1.0f);
        float d = (r == c) ? (1.0f - beta) : 0.0f;
        w1p[i] = beta * W1[i] + d;
        w2p[i] = beta * W2[i] + d;
    }
}

// ---------------- h0 GEMM: lane = node, wave = 16-col group; 4-deep feat prefetch pipeline ----------------
__global__ __launch_bounds__(256) void k_gemm0(const float* __restrict__ feat, const float* __restrict__ Win,
                                               const float* __restrict__ bin, const float* __restrict__ ns,
                                               float* __restrict__ hs, float* __restrict__ f0) {
    int lane = threadIdx.x & 63;
    int cg = __builtin_amdgcn_readfirstlane((threadIdx.x >> 6) & 3) * 16;
    int node = blockIdx.x * 64 + lane;
    int nodec = min(node, NN - 1);
    const float4* frow = (const float4*)(feat + (size_t)nodec * INF);
    const float* wbase = Win + cg;
    float acc[16];
#pragma unroll
    for (int c = 0; c < 16; c++) acc[c] = 0.0f;

    float4 r0 = frow[0], r1 = frow[1], r2 = frow[2], r3 = frow[3];
    for (int kk = 0; kk < INF / 4 - 4; kk += 4) {
        float4 n0 = frow[kk + 4], n1 = frow[kk + 5], n2 = frow[kk + 6], n3 = frow[kk + 7];
        float av[16] = {r0.x, r0.y, r0.z, r0.w, r1.x, r1.y, r1.z, r1.w,
                        r2.x, r2.y, r2.z, r2.w, r3.x, r3.y, r3.z, r3.w};
#pragma unroll
        for (int j = 0; j < 16; j++) {
            const float* wr = wbase + (size_t)(kk * 4 + j) * HID;
#pragma unroll
            for (int c = 0; c < 16; c++) acc[c] += av[j] * wr[c];
        }
        r0 = n0; r1 = n1; r2 = n2; r3 = n3;
    }
    {
        int kk = INF / 4 - 4;
        float av[16] = {r0.x, r0.y, r0.z, r0.w, r1.x, r1.y, r1.z, r1.w,
                        r2.x, r2.y, r2.z, r2.w, r3.x, r3.y, r3.z, r3.w};
#pragma unroll
        for (int j = 0; j < 16; j++) {
            const float* wr = wbase + (size_t)(kk * 4 + j) * HID;
#pragma unroll
            for (int c = 0; c < 16; c++) acc[c] += av[j] * wr[c];
        }
    }
    if (node < NN) {
        float nsv = ns[node];
        const float* bp = bin + cg;
        float4* hsp = (float4*)(hs + (size_t)node * HID + cg);
        float4* f0p = (float4*)(f0 + (size_t)node * HID + cg);
#pragma unroll
        for (int c4 = 0; c4 < 4; c4++) {
            float q0 = fmaxf(acc[c4 * 4 + 0] + bp[c4 * 4 + 0], 0.0f);
            float q1 = fmaxf(acc[c4 * 4 + 1] + bp[c4 * 4 + 1], 0.0f);
            float q2 = fmaxf(acc[c4 * 4 + 2] + bp[c4 * 4 + 2], 0.0f);
            float q3 = fmaxf(acc[c4 * 4 + 3] + bp[c4 * 4 + 3], 0.0f);
            float4 vs = {q0 * nsv, q1 * nsv, q2 * nsv, q3 * nsv};
            hsp[c4] = vs;
            float4 vf = {q0 * 0.1f, q1 * 0.1f, q2 * 0.1f, q3 * 0.1f};
            f0p[c4] = vf;
        }
    }
}

// ---------------- fused layer: agg (float4 gathers, 4 rows/instr) + matmul (LDS acts, scalar weights) ----------------
__global__ __launch_bounds__(256) void k_layer(const float* __restrict__ hs_in, const int* __restrict__ col,
                                               const int* __restrict__ row_start, const int* __restrict__ din,
                                               const float* __restrict__ nd, const float* __restrict__ f0,
                                               const float* __restrict__ w1p, const float* __restrict__ w2p,
                                               const float* __restrict__ bias, const float* __restrict__ ns,
                                               float* __restrict__ h, float* __restrict__ hs_out, int write_h) {
    __shared__ float fT[HID * PADN];
    __shared__ float f0T[HID * PADN];
    int tid = threadIdx.x;
    int lane = tid & 63;
    int wv = tid >> 6;
    int nb = blockIdx.x * 64;
    int grp = lane >> 4;         // edge slot within a 4-edge round
    int c4o = (lane & 15) << 2;  // feature dims [c4o, c4o+4)

    // stage f0 rows -> LDS transposed (coalesced 16B global reads)
    for (int i = tid; i < 64 * 16; i += 256) {
        int nl = i >> 4;
        int c4 = i & 15;
        int n = min(nb + nl, NN - 1);
        float4 v = *(const float4*)(f0 + (size_t)n * HID + c4 * 4);
        f0T[(c4 * 4 + 0) * PADN + nl] = v.x;
        f0T[(c4 * 4 + 1) * PADN + nl] = v.y;
        f0T[(c4 * 4 + 2) * PADN + nl] = v.z;
        f0T[(c4 * 4 + 3) * PADN + nl] = v.w;
    }

    // aggregation: wave wv handles 16 nodes serially; 4 edges per load round via lane groups
    int n0 = min(nb + wv * 16, NN - 1);
    int base_cur = row_start[n0];
    int deg_cur = din[n0];
    int idx_cur = (lane < min(deg_cur, 64)) ? col[base_cur + lane] : 0;

    for (int i = 0; i < 16; ++i) {
        int nl = wv * 16 + i;
        int n = min(nb + nl, NN - 1);
        // prefetch next node's first edge batch (takes col load off the critical path)
        int base_nx = 0, deg_nx = 0, idx_nx = 0;
        if (i < 15) {
            int n2 = min(nb + nl + 1, NN - 1);
            base_nx = row_start[n2];
            deg_nx = din[n2];
            idx_nx = (lane < min(deg_nx, 64)) ? col[base_nx + lane] : 0;
        }
        float ax = 0.0f, ay = 0.0f, az = 0.0f, aw = 0.0f;
        int deg = deg_cur, base = base_cur, idxv = idx_cur;
        for (int done = 0; done < deg;) {
            int cnt = min(64, deg - done);
            if (done) idxv = (lane < cnt) ? col[base + done + lane] : 0;
            int e = 0;
            // 16-edge window: 4 independent float4 gathers in flight
            for (; e + 16 <= cnt; e += 16) {
                int s0 = __shfl(idxv, e + grp, 64);
                int s1 = __shfl(idxv, e + 4 + grp, 64);
                int s2 = __shfl(idxv, e + 8 + grp, 64);
                int s3 = __shfl(idxv, e + 12 + grp, 64);
                float4 v0 = *(const float4*)(hs_in + (size_t)s0 * HID + c4o);
                float4 v1 = *(const float4*)(hs_in + (size_t)s1 * HID + c4o);
                float4 v2 = *(const float4*)(hs_in + (size_t)s2 * HID + c4o);
                float4 v3 = *(const float4*)(hs_in + (size_t)s3 * HID + c4o);
                ax += (v0.x + v1.x) + (v2.x + v3.x);
                ay += (v0.y + v1.y) + (v2.y + v3.y);
                az += (v0.z + v1.z) + (v2.z + v3.z);
                aw += (v0.w + v1.w) + (v2.w + v3.w);
            }
            if (e + 8 <= cnt) {
                int s0 = __shfl(idxv, e + grp, 64);
                int s1 = __shfl(idxv, e + 4 + grp, 64);
                float4 v0 = *(const float4*)(hs_in + (size_t)s0 * HID + c4o);
                float4 v1 = *(const float4*)(hs_in + (size_t)s1 * HID + c4o);
                ax += v0.x + v1.x;
                ay += v0.y + v1.y;
                az += v0.z + v1.z;
                aw += v0.w + v1.w;
                e += 8;
            }
            if (e < cnt) {
                int ei0 = e + grp;
                int ei1 = e + 4 + grp;
                int s0 = __shfl(idxv, ei0 & 63, 64);
                int s1 = __shfl(idxv, ei1 & 63, 64);
                if (ei0 < cnt) {
                    float4 v0 = *(const float4*)(hs_in + (size_t)s0 * HID + c4o);
                    ax += v0.x; ay += v0.y; az += v0.z; aw += v0.w;
                }
                if (ei1 < cnt) {
                    float4 v1 = *(const float4*)(hs_in + (size_t)s1 * HID + c4o);
                    ax += v1.x; ay += v1.y; az += v1.z; aw += v1.w;
                }
            }
            done += cnt;
        }
        // combine the 4 lane groups (each holds a partial over its edge subset)
        ax += __shfl_xor(ax, 16, 64); ax += __shfl_xor(ax, 32, 64);
        ay += __shfl_xor(ay, 16, 64); ay += __shfl_xor(ay, 32, 64);
        az += __shfl_xor(az, 16, 64); az += __shfl_xor(az, 32, 64);
        aw += __shfl_xor(aw, 16, 64); aw += __shfl_xor(aw, 32, 64);
        float sc = 0.9f * nd[n];
        if (grp == 0) {  // lanes 0..15 write 4 dims each, transposed
            fT[(c4o + 0) * PADN + nl] = ax * sc;
            fT[(c4o + 1) * PADN + nl] = ay * sc;
            fT[(c4o + 2) * PADN + nl] = az * sc;
            fT[(c4o + 3) * PADN + nl] = aw * sc;
        }
        base_cur = base_nx; deg_cur = deg_nx; idx_cur = idx_nx;
    }
    __syncthreads();

    // matmul: lane = node, wave = 16-col group; weights wave-uniform -> scalar loads
    int cg = __builtin_amdgcn_readfirstlane(wv) * 16;
    const float* w1b = w1p + cg;
    const float* w2b = w2p + cg;
    float acc[16];
#pragma unroll
    for (int c = 0; c < 16; c++) acc[c] = 0.0f;
    for (int kk = 0; kk < HID / 4; ++kk) {
#pragma unroll
        for (int j = 0; j < 4; j++) {
            int k = kk * 4 + j;
            float fk = fT[k * PADN + lane];
            float f0k = f0T[k * PADN + lane];
            const float* w1r = w1b + (size_t)k * HID;
            const float* w2r = w2b + (size_t)k * HID;
#pragma unroll
            for (int c = 0; c < 16; c++) acc[c] += fk * w1r[c] + f0k * w2r[c];
        }
    }
    int node = nb + lane;
    if (node < NN) {
        float nsv = ns[node];
        const float* bp = bias + cg;
        float4* hsp = (float4*)(hs_out + (size_t)node * HID + cg);
#pragma unroll
        for (int c4 = 0; c4 < 4; c4++) {
            float q0 = fmaxf(acc[c4 * 4 + 0] + bp[c4 * 4 + 0], 0.0f);
            float q1 = fmaxf(acc[c4 * 4 + 1] + bp[c4 * 4 + 1], 0.0f);
            float q2 = fmaxf(acc[c4 * 4 + 2] + bp[c4 * 4 + 2], 0.0f);
            float q3 = fmaxf(acc[c4 * 4 + 3] + bp[c4 * 4 + 3], 0.0f);
            float4 vs = {q0 * nsv, q1 * nsv, q2 * nsv, q3 * nsv};
            hsp[c4] = vs;
            if (write_h) {
                float4 v = {q0, q1, q2, q3};
                ((float4*)(h + (size_t)node * HID + cg))[c4] = v;
            }
        }
    }
}

// ---------------- output: block = 128 nodes; wave pair splits the 40 cols; LDS lse reduce ----------------
__global__ __launch_bounds__(256) void k_out(const float* __restrict__ h, const float* __restrict__ Wout,
                                             const float* __restrict__ bout, float* __restrict__ out) {
    __shared__ float red_mx[4][64];
    __shared__ float red_s[4][64];
    int tid = threadIdx.x;
    int lane = tid & 63;
    int wv = tid >> 6;
    int half = wv & 1;
    int grp = wv >> 1;
    int node = blockIdx.x * 128 + grp * 64 + lane;
    int nodec = min(node, NN - 1);
    float acc[20];
#pragma unroll
    for (int c = 0; c < 20; c++) acc[c] = 0.0f;
    const float4* hr = (const float4*)(h + (size_t)nodec * HID);
    const float* wb = Wout + half * 20;
    for (int kk = 0; kk < HID / 4; ++kk) {
        float4 a = hr[kk];
        float av[4] = {a.x, a.y, a.z, a.w};
#pragma unroll
        for (int j = 0; j < 4; j++) {
            const float* wr = wb + (size_t)(kk * 4 + j) * OUTF;
#pragma unroll
            for (int c = 0; c < 20; c++) acc[c] += av[j] * wr[c];
        }
    }
    const float* bp = bout + half * 20;
#pragma unroll
    for (int c = 0; c < 20; c++) acc[c] += bp[c];
    float mx = acc[0];
#pragma unroll
    for (int c = 1; c < 20; c++) mx = fmaxf(mx, acc[c]);
    red_mx[wv][lane] = mx;
    __syncthreads();
    float gmx = fmaxf(mx, red_mx[wv ^ 1][lane]);
    float s = 0.0f;
#pragma unroll
    for (int c = 0; c < 20; c++) s += expf(acc[c] - gmx);
    red_s[wv][lane] = s;
    __syncthreads();
    float lse = logf(s + red_s[wv ^ 1][lane]) + gmx;
    if (node < NN) {
        float4* op = (float4*)(out + (size_t)node * OUTF + half * 20);
#pragma unroll
        for (int q = 0; q < 5; q++) {
            float4 v;
            v.x = acc[q * 4 + 0] - lse;
            v.y = acc[q * 4 + 1] - lse;
            v.z = acc[q * 4 + 2] - lse;
            v.w = acc[q * 4 + 3] - lse;
            op[q] = v;
        }
    }
}

extern "C" void kernel_launch(void* const* d_in, const int* in_sizes, int n_in,
                              void* d_out, int out_size, void* d_ws, size_t ws_size,
                              hipStream_t stream) {
    const float* feat = (const float*)d_in[0];
    const float* Win  = (const float*)d_in[1];
    const float* bin  = (const float*)d_in[2];
    const float* W1   = (const float*)d_in[3];
    const float* W2   = (const float*)d_in[4];
    const float* bvec = (const float*)d_in[5];
    const float* Wout = (const float*)d_in[6];
    const float* bout = (const float*)d_in[7];
    const int*   src  = (const int*)d_in[8];
    const int*   dst  = (const int*)d_in[9];
    float* out = (float*)d_out;

    char* ws = (char*)d_ws;
    size_t off = 0;
    auto take = [&](size_t bytes) {
        void* p = ws + off;
        off += (bytes + 255) & ~(size_t)255;
        return p;
    };
    int* deg_out   = (int*)take(NN * 4);
    int* deg_in    = (int*)take(NN * 4);
    int* incl      = (int*)take(NN * 4);
    int* bsum      = (int*)take(256 * 4);
    int* row_start = (int*)take(NN * 4);
    int* cursor    = (int*)take(NN * 4);
    int* col       = (int*)take(NE * 4);
    float* nsrc    = (float*)take(NN * 4);
    float* ndst    = (float*)take(NN * 4);
    float* w1p     = (float*)take((size_t)NL * HID * HID * 4);
    float* w2p     = (float*)take((size_t)NL * HID * HID * 4);
    float* f0      = (float*)take((size_t)NN * HID * 4);
    float* hbuf    = (float*)take((size_t)NN * HID * 4);
    float* hsA     = (float*)take((size_t)NN * HID * 4);
    float* hsB     = (float*)take((size_t)NN * HID * 4);

    const int NB_N = (NN + 255) / 256;   // 196
    const int NB_E = (NE + 255) / 256;   // 3125
    const int NB_W = (NN + 63) / 64;     // 782
    const int NB_O = (NN + 127) / 128;   // 391

    hipMemsetAsync(deg_out, 0, NN * 4, stream);
    hipMemsetAsync(deg_in, 0, NN * 4, stream);

    k_deg<<<NB_E, 256, 0, stream>>>(src, dst, deg_out, deg_in);
    k_norm<<<NB_N, 256, 0, stream>>>(deg_out, deg_in, nsrc, ndst);
    k_scanA<<<NB_N, 256, 0, stream>>>(deg_in, incl, bsum);
    k_scanB<<<1, 256, 0, stream>>>(bsum, NB_N);
    k_scanC<<<NB_N, 256, 0, stream>>>(incl, deg_in, bsum, row_start, cursor);
    k_fill<<<NB_E, 256, 0, stream>>>(src, dst, cursor, col);
    k_wprep<<<(NL * HID * HID + 255) / 256, 256, 0, stream>>>(W1, W2, w1p, w2p);
    k_gemm0<<<NB_W, 256, 0, stream>>>(feat, Win, bin, nsrc, hsA, f0);

    // ping-pong hs buffers: k_layer gathers arbitrary rows of hs_in, so in-place update would race
    for (int l = 0; l < NL; ++l) {
        const float* hin = (l & 1) ? hsB : hsA;
        float* hout = (l & 1) ? hsA : hsB;
        k_layer<<<NB_W, 256, 0, stream>>>(hin, col, row_start, deg_in, ndst, f0,
                                          w1p + l * HID * HID, w2p + l * HID * HID,
                                          bvec + l * HID, nsrc, hbuf, hout, (l == NL - 1) ? 1 : 0);
    }
    k_out<<<NB_O, 256, 0, stream>>>(hbuf, Wout, bout, out);
}